// Round 1
// baseline (493.471 us; speedup 1.0000x reference)
//
#include <hip/hip_runtime.h>

// ---------------------------------------------------------------------------
// 3-layer GraphSAGE (mean aggregation) on MI355X.
// Strategy: build CSR per call (hist -> scan -> fill), then per layer:
//   k_agg  : atomic-free mean aggregation, one wave per node, float2 lanes
//   k_gemm : fused out = agg@Wl + h@Wr + b (+ReLU), 64-node tiles,
//            K chunked by 64, W-chunk + transposed-input-chunk in LDS (48KB)
// ---------------------------------------------------------------------------

__global__ void k_hist(const int* __restrict__ dst, int* __restrict__ deg, int E)
{
    int i = blockIdx.x * blockDim.x + threadIdx.x;
    int stride = gridDim.x * blockDim.x;
    for (; i < E; i += stride)
        atomicAdd(&deg[dst[i]], 1);
}

// Single-block exclusive scan of deg[0..n-1] -> rp and cur; rp[n] = total.
// 1024 threads, 4 elements/thread/iter (4096 per iter).
__global__ __launch_bounds__(1024) void k_scan(const int* __restrict__ deg,
                                               int* __restrict__ rp,
                                               int* __restrict__ cur, int n)
{
    __shared__ int wsum[16];
    __shared__ int carry_s;
    int tid = threadIdx.x, lane = tid & 63, w = tid >> 6;
    if (tid == 0) carry_s = 0;
    __syncthreads();
    for (int base = 0; base < n; base += 4096) {
        int i = base + tid * 4;
        int4 v = make_int4(0, 0, 0, 0);
        if (i + 3 < n) v = *(const int4*)(deg + i);
        else {
            if (i     < n) v.x = deg[i];
            if (i + 1 < n) v.y = deg[i + 1];
            if (i + 2 < n) v.z = deg[i + 2];
            if (i + 3 < n) v.w = deg[i + 3];
        }
        int t = v.x + v.y + v.z + v.w;
        int s = t;
        #pragma unroll
        for (int d = 1; d < 64; d <<= 1) { int u = __shfl_up(s, d); if (lane >= d) s += u; }
        if (lane == 63) wsum[w] = s;
        __syncthreads();
        if (w == 0 && lane < 16) {
            int u = wsum[lane];
            #pragma unroll
            for (int d = 1; d < 16; d <<= 1) { int y = __shfl_up(u, d); if (lane >= d) u += y; }
            wsum[lane] = u;   // inclusive scan of wave totals
        }
        __syncthreads();
        int carry = carry_s;
        int off = carry + (w ? wsum[w - 1] : 0) + (s - t);
        int r0 = off, r1 = r0 + v.x, r2 = r1 + v.y, r3 = r2 + v.z;
        if (i + 3 < n) {
            *(int4*)(rp + i)  = make_int4(r0, r1, r2, r3);
            *(int4*)(cur + i) = make_int4(r0, r1, r2, r3);
        } else {
            if (i     < n) { rp[i]     = r0; cur[i]     = r0; }
            if (i + 1 < n) { rp[i + 1] = r1; cur[i + 1] = r1; }
            if (i + 2 < n) { rp[i + 2] = r2; cur[i + 2] = r2; }
            if (i + 3 < n) { rp[i + 3] = r3; cur[i + 3] = r3; }
        }
        __syncthreads();
        if (tid == 1023) carry_s = carry + wsum[15];
    }
    __syncthreads();
    if (tid == 0) rp[n] = carry_s;
}

__global__ void k_fill(const int* __restrict__ src, const int* __restrict__ dst,
                       int* __restrict__ cur, int* __restrict__ col, int E)
{
    int i = blockIdx.x * blockDim.x + threadIdx.x;
    int stride = gridDim.x * blockDim.x;
    for (; i < E; i += stride) {
        int p = atomicAdd(&cur[dst[i]], 1);
        col[p] = src[i];
    }
}

// Mean aggregation: one wave per node; lane l holds dims 2l, 2l+1.
__global__ __launch_bounds__(256) void k_agg(const float* __restrict__ h,
                                             const int* __restrict__ rp,
                                             const int* __restrict__ col,
                                             float* __restrict__ agg, int nNodes)
{
    int gw   = (blockIdx.x * blockDim.x + threadIdx.x) >> 6;
    int lane = threadIdx.x & 63;
    int nw   = (gridDim.x * blockDim.x) >> 6;
    for (int n = gw; n < nNodes; n += nw) {
        int s = rp[n], e = rp[n + 1];
        float a0 = 0.f, a1 = 0.f, b0 = 0.f, b1 = 0.f;
        int i = s;
        for (; i + 2 <= e; i += 2) {            // 2 neighbors in flight for MLP
            int c0 = col[i], c1 = col[i + 1];
            float2 v0 = *(const float2*)(h + (size_t)c0 * 128 + lane * 2);
            float2 v1 = *(const float2*)(h + (size_t)c1 * 128 + lane * 2);
            a0 += v0.x; a1 += v0.y;
            b0 += v1.x; b1 += v1.y;
        }
        if (i < e) {
            int c0 = col[i];
            float2 v0 = *(const float2*)(h + (size_t)c0 * 128 + lane * 2);
            a0 += v0.x; a1 += v0.y;
        }
        float inv = (e > s) ? (1.f / (float)(e - s)) : 0.f;
        float2 o; o.x = (a0 + b0) * inv; o.y = (a1 + b1) * inv;
        *(float2*)(agg + (size_t)n * 128 + lane * 2) = o;
    }
}

// Fused SAGE linear: out = agg @ Wl + h @ Wr + b, optional ReLU.
// 64-node tile/block; K=256 done as 4 chunks of 64 (Wl k0,Wl k1,Wr k0,Wr k1).
// LDS: W chunk [64][128] (32KB) + transposed input chunk [64][64] (16KB).
// Thread (ng,cg) owns 4 nodes x 8 cols. NOTE: hmat/out may alias (in-place
// rows, block-exclusive) -> no __restrict__ on them.
__global__ __launch_bounds__(256) void k_gemm(const float* __restrict__ agg,
                                              const float* hmat,
                                              const float* __restrict__ Wl,
                                              const float* __restrict__ Wr,
                                              const float* __restrict__ bias,
                                              float* out, int relu, int nNodes)
{
    __shared__ float Wc[64 * 128];   // [k][c]
    __shared__ float inT[64 * 64];   // [k][n]
    int tid = threadIdx.x;
    int node0 = blockIdx.x * 64;
    int ng = tid >> 4, cg = tid & 15;
    float acc[4][8];
    #pragma unroll
    for (int a = 0; a < 4; ++a)
        #pragma unroll
        for (int b = 0; b < 8; ++b) acc[a][b] = 0.f;

    int sn  = tid >> 2;              // staging node 0..63
    int sk  = (tid & 3) * 16;        // staging k offset within chunk
    int gsn = node0 + sn;

    #pragma unroll 1
    for (int ch = 0; ch < 4; ++ch) {
        const float* W  = (ch < 2) ? Wl : Wr;
        const float* in = (ch < 2) ? agg : hmat;
        int kc = (ch & 1) * 64;
        __syncthreads();             // previous chunk's LDS reads done
        // stage W rows kc..kc+63 (coalesced contiguous copy)
        {
            const float4* W4  = (const float4*)(W + kc * 128);
            float4* Wc4 = (float4*)Wc;
            #pragma unroll
            for (int it = 0; it < 8; ++it)
                Wc4[tid + it * 256] = W4[tid + it * 256];
        }
        // stage input chunk transposed: inT[k][n] = in[node0+n][kc+k]
        if (gsn < nNodes) {
            const float4* s4 = (const float4*)(in + (size_t)gsn * 128 + kc + sk);
            #pragma unroll
            for (int j = 0; j < 4; ++j) {
                float4 v = s4[j];
                int k = sk + j * 4;
                inT[(k + 0) * 64 + sn] = v.x;
                inT[(k + 1) * 64 + sn] = v.y;
                inT[(k + 2) * 64 + sn] = v.z;
                inT[(k + 3) * 64 + sn] = v.w;
            }
        } else {
            #pragma unroll
            for (int j = 0; j < 4; ++j) {
                int k = sk + j * 4;
                inT[(k + 0) * 64 + sn] = 0.f;
                inT[(k + 1) * 64 + sn] = 0.f;
                inT[(k + 2) * 64 + sn] = 0.f;
                inT[(k + 3) * 64 + sn] = 0.f;
            }
        }
        __syncthreads();
        #pragma unroll 8
        for (int k = 0; k < 64; ++k) {
            float4 a4 = *(const float4*)(inT + k * 64 + ng * 4);
            float4 w0 = *(const float4*)(Wc + k * 128 + cg * 8);
            float4 w1 = *(const float4*)(Wc + k * 128 + cg * 8 + 4);
            float av[4] = {a4.x, a4.y, a4.z, a4.w};
            float wv[8] = {w0.x, w0.y, w0.z, w0.w, w1.x, w1.y, w1.z, w1.w};
            #pragma unroll
            for (int a = 0; a < 4; ++a)
                #pragma unroll
                for (int b = 0; b < 8; ++b)
                    acc[a][b] = fmaf(av[a], wv[b], acc[a][b]);
        }
    }
    // epilogue: bias (+ReLU) + store
    float bv[8];
    #pragma unroll
    for (int b = 0; b < 8; ++b) bv[b] = bias[cg * 8 + b];
    #pragma unroll
    for (int a = 0; a < 4; ++a) {
        int gn = node0 + ng * 4 + a;
        if (gn >= nNodes) break;
        float r[8];
        #pragma unroll
        for (int b = 0; b < 8; ++b) {
            float v = acc[a][b] + bv[b];
            r[b] = relu ? fmaxf(v, 0.f) : v;
        }
        float4* o4 = (float4*)(out + (size_t)gn * 128 + cg * 8);
        o4[0] = *(float4*)(r);
        o4[1] = *(float4*)(r + 4);
    }
}

extern "C" void kernel_launch(void* const* d_in, const int* in_sizes, int n_in,
                              void* d_out, int out_size, void* d_ws, size_t ws_size,
                              hipStream_t stream)
{
    const float* x   = (const float*)d_in[0];
    const int*   ei  = (const int*)d_in[1];
    const float* Wl1 = (const float*)d_in[2];
    const float* b1  = (const float*)d_in[3];
    const float* Wr1 = (const float*)d_in[4];
    const float* Wl2 = (const float*)d_in[5];
    const float* b2  = (const float*)d_in[6];
    const float* Wr2 = (const float*)d_in[7];
    const float* Wl3 = (const float*)d_in[8];
    const float* b3  = (const float*)d_in[9];
    const float* Wr3 = (const float*)d_in[10];
    float* out = (float*)d_out;

    int N = in_sizes[0] / 128;
    int E = in_sizes[1] / 2;
    const int* srcp = ei;        // edge_index[0]
    const int* dstp = ei + E;    // edge_index[1]

    // workspace layout (16B-aligned regions)
    float* A  = (float*)d_ws;                       // agg        N*128 f32
    float* B  = A + (size_t)N * 128;                // h          N*128 f32
    int* deg  = (int*)(B + (size_t)N * 128);        // N ints
    int* rp   = deg + ((N + 3) & ~3);               // N+1 ints
    int* cur  = rp + ((N + 4) & ~3);                // N ints (16B aligned)
    int* col  = cur + ((N + 3) & ~3);               // E ints

    hipMemsetAsync(deg, 0, (size_t)N * sizeof(int), stream);
    k_hist<<<1024, 256, 0, stream>>>(dstp, deg, E);
    k_scan<<<1, 1024, 0, stream>>>(deg, rp, cur, N);
    k_fill<<<1024, 256, 0, stream>>>(srcp, dstp, cur, col, E);

    int gb = (N + 63) / 64;
    // layer 1
    k_agg<<<2048, 256, 0, stream>>>(x, rp, col, A, N);
    k_gemm<<<gb, 256, 0, stream>>>(A, x, Wl1, Wr1, b1, B, 1, N);
    // layer 2 (h2 overwrites B row-wise in place; block-exclusive rows safe)
    k_agg<<<2048, 256, 0, stream>>>(B, rp, col, A, N);
    k_gemm<<<gb, 256, 0, stream>>>(A, B, Wl2, Wr2, b2, B, 1, N);
    // layer 3
    k_agg<<<2048, 256, 0, stream>>>(B, rp, col, A, N);
    k_gemm<<<gb, 256, 0, stream>>>(A, B, Wl3, Wr3, b3, out, 0, N);
}